// Round 3
// baseline (27.823 us; speedup 1.0000x reference)
//
#include <hip/hip_runtime.h>

// EdgeSelectionRL: out[b,i,j] = sigmoid( sum_h relu(A[b,i,h] + Cc[b,j,h]) * w2[h] + b2 )
// A = xa·Wa^T + b1, Cc = xa·Wb^T.  B=8, C=256, F=128, H=256.
// R3: k1 -> MFMA (16x16x32_f16, direct global fragment loads, zero LDS),
//     k0 pre-converts inputs to fp16. k2 unchanged (fp16 dot2, ~3-5us model).

typedef _Float16 h2 __attribute__((ext_vector_type(2)));
typedef _Float16 h4 __attribute__((ext_vector_type(4)));
typedef _Float16 h8 __attribute__((ext_vector_type(8)));
typedef float    f4 __attribute__((ext_vector_type(4)));

constexpr int B  = 8;
constexpr int C  = 256;
constexpr int F  = 128;
constexpr int H  = 256;
constexpr int F2 = 2 * F;     // 256
constexpr int HOCT = H / 8;   // 32

#if __has_builtin(__builtin_amdgcn_fdot2)
__device__ __forceinline__ float fdot2(h2 a, h2 b, float c) {
    return __builtin_amdgcn_fdot2(a, b, c, false);
}
#else
__device__ __forceinline__ float fdot2(h2 a, h2 b, float c) {
    return c + (float)a.x * (float)b.x + (float)a.y * (float)b.y;
}
#endif

// ---------------- Kernel 0: f32 -> f16 conversion ----------------
// xa: 65536 float4 quads, W1: 16384 quads, w2: 64 quads. Total 81984.
__global__ __launch_bounds__(256) void k0_cvt(
    const float* __restrict__ xa, const float* __restrict__ W1,
    const float* __restrict__ w2,
    _Float16* __restrict__ Xh, _Float16* __restrict__ Wh,
    _Float16* __restrict__ w2h)
{
    const int idx = blockIdx.x * 256 + threadIdx.x;
    if (idx >= 81984) return;
    float4 v;
    _Float16* dst;
    if (idx < 65536)      { v = ((const float4*)xa)[idx];          dst = Xh  + idx * 4; }
    else if (idx < 81920) { v = ((const float4*)W1)[idx - 65536];  dst = Wh  + (idx - 65536) * 4; }
    else                  { v = ((const float4*)w2)[idx - 81920];  dst = w2h + (idx - 81920) * 4; }
    h4 o = {(_Float16)v.x, (_Float16)v.y, (_Float16)v.z, (_Float16)v.w};
    *(h4*)dst = o;
}

// ---------------- Kernel 1: fused projections via MFMA ----------------
// One wave = one 16m x 16h tile-pair (A and Cc). K-loop 4 x 32. No LDS.
// A-frag: lane l holds X[m0 + (l&15)][k0 + (l>>4)*8 + j]  (16B contiguous)
// B-frag: lane l holds W[h0 + (l&15)][k0 + (l>>4)*8 + j]  (16B contiguous)
// D: lane l, reg r -> row m0+(l>>4)*4+r, col h0+(l&15)   [m89-verified]
__global__ __launch_bounds__(256) void k1_mfma(
    const _Float16* __restrict__ Xh, const _Float16* __restrict__ Wh,
    const float* __restrict__ b1,
    _Float16* __restrict__ Ah, _Float16* __restrict__ CP8)
{
    const int t  = threadIdx.x;
    const int w  = blockIdx.x * 4 + (t >> 6);   // 0..2047
    const int l  = t & 63;
    const int m0 = (w >> 4) * 16;               // 0..2032 (m = b*C + i)
    const int h0 = (w & 15) * 16;
    const int lm = l & 15;
    const int lk = (l >> 4) * 8;

    const _Float16* xp = Xh + (size_t)(m0 + lm) * F  + lk;
    const _Float16* wp = Wh + (size_t)(h0 + lm) * F2 + lk;

    f4 accA = {0.f, 0.f, 0.f, 0.f};
    f4 accC = {0.f, 0.f, 0.f, 0.f};
    #pragma unroll
    for (int kk = 0; kk < 4; ++kk) {
        h8 af = *(const h8*)(xp + kk * 32);
        h8 ba = *(const h8*)(wp + kk * 32);
        h8 bb = *(const h8*)(wp + F + kk * 32);
        accA = __builtin_amdgcn_mfma_f32_16x16x32_f16(af, ba, accA, 0, 0, 0);
        accC = __builtin_amdgcn_mfma_f32_16x16x32_f16(af, bb, accC, 0, 0, 0);
    }

    const int h   = h0 + lm;
    const float bh = b1[h];
    const int mb  = m0 + (l >> 4) * 4;
    #pragma unroll
    for (int r = 0; r < 4; ++r) {
        const int m = mb + r;
        Ah[(size_t)m * H + h] = (_Float16)(accA[r] + bh);
        // h-octet-packed Cc: CP8[((b*HOCT + h/8)*C + i)*8 + (h&7)], b=m>>8, i=m&255
        CP8[(((size_t)((m >> 8) * HOCT + (h >> 3)) * C + (m & 255)) << 3) + (h & 7)]
            = (_Float16)accC[r];
    }
}

// ---------------- Kernel 2: pairwise relu-dot + sigmoid --------------------
// Block = (b, 8 i-rows): 1024 threads = 256 j x 4 h-splits (16 waves).
// A octets wave-uniform -> s_load; Cc octets 16B/lane coalesced, slab read once.
constexpr int TI = 8;
constexpr int HS = 4;

__global__ __launch_bounds__(1024) void k2_pair(
    const _Float16* __restrict__ Ah, const _Float16* __restrict__ CP8,
    const _Float16* __restrict__ w2h, const float* __restrict__ b2p,
    float* __restrict__ out)
{
    __shared__ float red[(HS - 1) * TI * C];   // 24 KB
    const int t   = threadIdx.x;
    const int j   = t & 255;
    const int hs  = t >> 8;                    // wave-uniform
    const int blk = blockIdx.x;
    const int it  = blk & 31;
    const int b   = blk >> 5;
    const int i0  = it * TI;

    float acc[TI];
    #pragma unroll
    for (int ii = 0; ii < TI; ++ii) acc[ii] = 0.f;

    const int g0 = hs * (HOCT / HS);           // 8 octets per split
    const _Float16* Ab = Ah + (size_t)(b * C + i0) * H;

    union U { h8 v; h2 p[4]; };
    #pragma unroll 2
    for (int g = 0; g < HOCT / HS; ++g) {
        const int hb = g0 + g;
        h8 cc = *(const h8*)(CP8 + (((size_t)(b * HOCT + hb) * C + j) << 3));
        U uw; uw.v = *(const h8*)(w2h + hb * 8);          // uniform
        #pragma unroll
        for (int ii = 0; ii < TI; ++ii) {
            h8 av = *(const h8*)(Ab + ii * H + hb * 8);   // uniform -> s_load
            h8 s = av + cc;                                // v_pk_add_f16
            h8 z = {0, 0, 0, 0, 0, 0, 0, 0};
            s = __builtin_elementwise_max(s, z);           // v_pk_max_f16
            U us; us.v = s;
            float a0 = acc[ii];
            a0 = fdot2(us.p[0], uw.p[0], a0);              // v_dot2_f32_f16
            a0 = fdot2(us.p[1], uw.p[1], a0);
            a0 = fdot2(us.p[2], uw.p[2], a0);
            a0 = fdot2(us.p[3], uw.p[3], a0);
            acc[ii] = a0;
        }
    }

    if (hs > 0) {
        #pragma unroll
        for (int ii = 0; ii < TI; ++ii)
            red[((hs - 1) * TI + ii) * C + j] = acc[ii];
    }
    __syncthreads();
    if (hs == 0) {
        const float bb = b2p[0];
        #pragma unroll
        for (int ii = 0; ii < TI; ++ii) {
            float x = acc[ii]
                    + red[(0 * TI + ii) * C + j]
                    + red[(1 * TI + ii) * C + j]
                    + red[(2 * TI + ii) * C + j] + bb;
            out[(size_t)(b * C + i0 + ii) * C + j] = 1.f / (1.f + __expf(-x));
        }
    }
}

extern "C" void kernel_launch(void* const* d_in, const int* in_sizes, int n_in,
                              void* d_out, int out_size, void* d_ws, size_t ws_size,
                              hipStream_t stream) {
    const float* xa = (const float*)d_in[0];
    const float* W1 = (const float*)d_in[1];
    const float* b1 = (const float*)d_in[2];
    const float* w2 = (const float*)d_in[3];
    const float* b2 = (const float*)d_in[4];
    float* out = (float*)d_out;

    _Float16* Ah  = (_Float16*)d_ws;                  // 1 MB
    _Float16* CP8 = Ah  + (size_t)B * C * H;          // 1 MB
    _Float16* w2h = CP8 + (size_t)B * H * C;          // 512 B
    _Float16* Xh  = w2h + 512;                        // 512 KB (aligned)
    _Float16* Wh  = Xh  + (size_t)B * C * F;          // 128 KB

    k0_cvt <<<321, 256, 0, stream>>>(xa, W1, w2, Xh, Wh, w2h);
    k1_mfma<<<512, 256, 0, stream>>>(Xh, Wh, b1, Ah, CP8);
    k2_pair<<<B * (C / TI), 1024, 0, stream>>>(Ah, CP8, w2h, b2, out);
}

// Round 4
// 23.842 us; speedup vs baseline: 1.1670x; 1.1670x over previous
//
#include <hip/hip_runtime.h>

// EdgeSelectionRL: out[b,i,j] = sigmoid( sum_h relu(A[b,i,h] + Cc[b,j,h]) * w2[h] + b2 )
// A = xa·Wa^T + b1, Cc = xa·Wb^T.  B=8, C=256, F=128, H=256.
// R4: 2 kernels. k1 = in-register f32->f16 cvt + MFMA projection (no k0, no LDS),
// each wave does 2 m-tiles x 1 h-tile. k2 unchanged (fp16 dot2, ~2.6us VALU floor).
// Model: ~20us fixed pedestal (graph/launch/sync) + work; this removes one launch.

typedef _Float16 h2 __attribute__((ext_vector_type(2)));
typedef _Float16 h8 __attribute__((ext_vector_type(8)));
typedef float    f4 __attribute__((ext_vector_type(4)));

constexpr int B  = 8;
constexpr int C  = 256;
constexpr int F  = 128;
constexpr int H  = 256;
constexpr int F2 = 2 * F;     // 256
constexpr int HOCT = H / 8;   // 32

#if __has_builtin(__builtin_amdgcn_fdot2)
__device__ __forceinline__ float fdot2(h2 a, h2 b, float c) {
    return __builtin_amdgcn_fdot2(a, b, c, false);
}
#else
__device__ __forceinline__ float fdot2(h2 a, h2 b, float c) {
    return c + (float)a.x * (float)b.x + (float)a.y * (float)b.y;
}
#endif

__device__ __forceinline__ h8 cvt8(float4 a, float4 b) {
    h8 r;
    r[0] = (_Float16)a.x; r[1] = (_Float16)a.y; r[2] = (_Float16)a.z; r[3] = (_Float16)a.w;
    r[4] = (_Float16)b.x; r[5] = (_Float16)b.y; r[6] = (_Float16)b.z; r[7] = (_Float16)b.w;
    return r;
}

// ---------------- Kernel 1: fused cvt + projections via MFMA ----------------
// 256 blocks x 256 thr = 1024 waves. Wave w: mg = w>>4 (2 m-tiles at mg*32),
// ht = w&15 (h0 = ht*16). Direct f32 global fragment loads, cvt in-register.
// D layout (m89): lane l, reg r -> row m0+(l>>4)*4+r, col h0+(l&15).
__global__ __launch_bounds__(256) void k1_mfma(
    const float* __restrict__ xa, const float* __restrict__ W1,
    const float* __restrict__ b1, const float* __restrict__ w2,
    _Float16* __restrict__ Ah, _Float16* __restrict__ CP8,
    _Float16* __restrict__ w2h)
{
    const int t  = threadIdx.x;
    const int w  = blockIdx.x * 4 + (t >> 6);   // 0..1023
    const int l  = t & 63;
    const int mg = w >> 4;                      // 0..63
    const int h0 = (w & 15) * 16;
    const int lm = l & 15;
    const int lk = (l >> 4) * 8;
    const int m0 = mg * 32;

    // A-frags: 2 m-tiles x 4 k-steps, loaded f32 -> cvt f16
    h8 af[2][4];
    const float* xp0 = xa + (size_t)(m0 + lm) * F + lk;
    const float* xp1 = xp0 + 16 * F;
    #pragma unroll
    for (int kk = 0; kk < 4; ++kk) {
        float4 a0 = *(const float4*)(xp0 + kk * 32);
        float4 a1 = *(const float4*)(xp0 + kk * 32 + 4);
        float4 b0 = *(const float4*)(xp1 + kk * 32);
        float4 b1v = *(const float4*)(xp1 + kk * 32 + 4);
        af[0][kk] = cvt8(a0, a1);
        af[1][kk] = cvt8(b0, b1v);
    }

    const float* wp = W1 + (size_t)(h0 + lm) * F2 + lk;
    f4 accA0 = {0.f,0.f,0.f,0.f}, accA1 = {0.f,0.f,0.f,0.f};
    f4 accC0 = {0.f,0.f,0.f,0.f}, accC1 = {0.f,0.f,0.f,0.f};
    #pragma unroll
    for (int kk = 0; kk < 4; ++kk) {
        float4 wa0 = *(const float4*)(wp + kk * 32);
        float4 wa1 = *(const float4*)(wp + kk * 32 + 4);
        float4 wb0 = *(const float4*)(wp + F + kk * 32);
        float4 wb1 = *(const float4*)(wp + F + kk * 32 + 4);
        h8 ba = cvt8(wa0, wa1);
        h8 bb = cvt8(wb0, wb1);
        accA0 = __builtin_amdgcn_mfma_f32_16x16x32_f16(af[0][kk], ba, accA0, 0, 0, 0);
        accC0 = __builtin_amdgcn_mfma_f32_16x16x32_f16(af[0][kk], bb, accC0, 0, 0, 0);
        accA1 = __builtin_amdgcn_mfma_f32_16x16x32_f16(af[1][kk], ba, accA1, 0, 0, 0);
        accC1 = __builtin_amdgcn_mfma_f32_16x16x32_f16(af[1][kk], bb, accC1, 0, 0, 0);
    }

    const int h  = h0 + lm;
    const float bh = b1[h];
    #pragma unroll
    for (int mt = 0; mt < 2; ++mt) {
        const f4 aA = mt ? accA1 : accA0;
        const f4 aC = mt ? accC1 : accC0;
        const int mb = m0 + mt * 16 + (l >> 4) * 4;
        #pragma unroll
        for (int r = 0; r < 4; ++r) {
            const int m = mb + r;
            Ah[(size_t)m * H + h] = (_Float16)(aA[r] + bh);
            // h-octet-packed Cc: CP8[((b*HOCT + h/8)*C + i)*8 + (h&7)], b=m>>8, i=m&255
            CP8[(((size_t)((m >> 8) * HOCT + (h >> 3)) * C + (m & 255)) << 3) + (h & 7)]
                = (_Float16)aC[r];
        }
    }

    if (blockIdx.x == 0 && t < 128) {   // w2 -> fp16 once (k2 reads it next dispatch)
        float2 wv = ((const float2*)w2)[t];
        h2 hv = {(_Float16)wv.x, (_Float16)wv.y};
        ((h2*)w2h)[t] = hv;
    }
}

// ---------------- Kernel 2: pairwise relu-dot + sigmoid --------------------
// Block = (b, 8 i-rows): 1024 threads = 256 j x 4 h-splits (16 waves).
// A octets same-address per wave (L1-hit); cc octets 16B/lane coalesced.
constexpr int TI = 8;
constexpr int HS = 4;

__global__ __launch_bounds__(1024) void k2_pair(
    const _Float16* __restrict__ Ah, const _Float16* __restrict__ CP8,
    const _Float16* __restrict__ w2h, const float* __restrict__ b2p,
    float* __restrict__ out)
{
    __shared__ float red[(HS - 1) * TI * C];   // 24 KB
    const int t   = threadIdx.x;
    const int j   = t & 255;
    const int hs  = t >> 8;                    // wave-uniform
    const int blk = blockIdx.x;
    const int it  = blk & 31;
    const int b   = blk >> 5;
    const int i0  = it * TI;

    float acc[TI];
    #pragma unroll
    for (int ii = 0; ii < TI; ++ii) acc[ii] = 0.f;

    const int g0 = hs * (HOCT / HS);           // 8 octets per split
    const _Float16* Ab = Ah + (size_t)(b * C + i0) * H;

    union U { h8 v; h2 p[4]; };
    #pragma unroll 2
    for (int g = 0; g < HOCT / HS; ++g) {
        const int hb = g0 + g;
        h8 cc = *(const h8*)(CP8 + (((size_t)(b * HOCT + hb) * C + j) << 3));
        U uw; uw.v = *(const h8*)(w2h + hb * 8);          // 512B table, L1
        #pragma unroll
        for (int ii = 0; ii < TI; ++ii) {
            h8 av = *(const h8*)(Ab + ii * H + hb * 8);   // same addr per wave
            h8 s = av + cc;                                // v_pk_add_f16
            h8 z = {0, 0, 0, 0, 0, 0, 0, 0};
            s = __builtin_elementwise_max(s, z);           // v_pk_max_f16
            U us; us.v = s;
            float a0 = acc[ii];
            a0 = fdot2(us.p[0], uw.p[0], a0);              // v_dot2_f32_f16
            a0 = fdot2(us.p[1], uw.p[1], a0);
            a0 = fdot2(us.p[2], uw.p[2], a0);
            a0 = fdot2(us.p[3], uw.p[3], a0);
            acc[ii] = a0;
        }
    }

    if (hs > 0) {
        #pragma unroll
        for (int ii = 0; ii < TI; ++ii)
            red[((hs - 1) * TI + ii) * C + j] = acc[ii];
    }
    __syncthreads();
    if (hs == 0) {
        const float bb = b2p[0];
        #pragma unroll
        for (int ii = 0; ii < TI; ++ii) {
            float x = acc[ii]
                    + red[(0 * TI + ii) * C + j]
                    + red[(1 * TI + ii) * C + j]
                    + red[(2 * TI + ii) * C + j] + bb;
            out[(size_t)(b * C + i0 + ii) * C + j] = 1.f / (1.f + __expf(-x));
        }
    }
}

extern "C" void kernel_launch(void* const* d_in, const int* in_sizes, int n_in,
                              void* d_out, int out_size, void* d_ws, size_t ws_size,
                              hipStream_t stream) {
    const float* xa = (const float*)d_in[0];
    const float* W1 = (const float*)d_in[1];
    const float* b1 = (const float*)d_in[2];
    const float* w2 = (const float*)d_in[3];
    const float* b2 = (const float*)d_in[4];
    float* out = (float*)d_out;

    _Float16* Ah  = (_Float16*)d_ws;                  // 1 MB
    _Float16* CP8 = Ah  + (size_t)B * C * H;          // 1 MB
    _Float16* w2h = CP8 + (size_t)B * H * C;          // 512 B

    k1_mfma<<<256, 256, 0, stream>>>(xa, W1, b1, w2, Ah, CP8, w2h);
    k2_pair<<<B * (C / TI), 1024, 0, stream>>>(Ah, CP8, w2h, b2, out);
}